// Round 17
// baseline (388.543 us; speedup 1.0000x reference)
//
#include <hip/hip_runtime.h>
#include <hip/hip_bf16.h>
#include <stdint.h>

// ---- problem constants ----
#define NCLS   19
#define CACHE  5000
#define NTILE  313            // 16-col tiles per class (313*16 = 5008, 8 pad cols)
#define DDIM   256
#define NANCH  102
#define NVIEW  10
#define NROWS  1020
#define NSUB   13             // column sub-chunks per class
#define NCHUNK (NCLS*NSUB)    // 247
#define NWG    (4*NCHUNK)     // 988 pass1 blocks
#define SCALE_A 20.6099319733f   // (1/0.07) * log2(e): MFMA acc = s * log2(e)
#define LN2     0.69314718056f

using bf16x8 = __attribute__((ext_vector_type(8))) __bf16;
using f32x4  = __attribute__((ext_vector_type(4))) float;

#if __has_builtin(__builtin_amdgcn_exp2f)
#define EXP2(x) __builtin_amdgcn_exp2f(x)
#else
#define EXP2(x) __expf((x) * LN2)
#endif

static __device__ __forceinline__ unsigned short f2bf(float x) {
    unsigned int u = __float_as_uint(x);
    unsigned int r = (u + 0x7FFFu + ((u >> 16) & 1u)) >> 16;
    return (unsigned short)r;
}

// Raw barrier WITHOUT the vmcnt(0) drain __syncthreads emits (m97/m233).
#define BARRIER_NODRAIN() do {                                   \
        asm volatile("s_waitcnt lgkmcnt(0)" ::: "memory");       \
        __builtin_amdgcn_sched_barrier(0);                       \
        __builtin_amdgcn_s_barrier();                            \
        __builtin_amdgcn_sched_barrier(0);                       \
    } while (0)

// ---- anchors: view-major [1024][256] bf16, pre-scaled by (1/T)*log2(e) ----
__global__ __launch_bounds__(256) void conv_anchor2(const float* __restrict__ X,
                                                    unsigned short* __restrict__ Abf) {
    int n = blockIdx.x;     // 0..1023
    int k = threadIdx.x;    // 0..255
    float v = 0.f;
    if (n < NROWS) {
        int vv = n / NANCH, a = n - vv * NANCH;
        v = X[((size_t)a * NVIEW + vv) * DDIM + k] * SCALE_A;
    }
    Abf[(size_t)n * DDIM + k] = f2bf(v);
}

// ---- fused pass: R16 structure, occupancy raised to 4 blocks/CU ----
// R16's VGPR_Count was 120 <= 128 = the 4-waves/SIMD cap, so (256,4) is now
// affordable without spill (R6's failure had a ~240-reg live set). 16 waves/CU
// from 4 independent blocks cross-cover each block's barrier/EPI phases.
__global__ __launch_bounds__(256, 4) void pass1_kernel(
    const unsigned short* __restrict__ Abf, const float* __restrict__ Qf,
    const int* __restrict__ y,
    float* __restrict__ Pt, float* __restrict__ Pe, float* __restrict__ Ps)
{
    __shared__ unsigned char lds[2][8192];   // 2 x 8KB bf16 fragment tiles

    // bijective XCD swizzle (m204): nwg=988, 8 XCDs, q=123, r=4.
    int orig = blockIdx.x;
    int xcd = orig & 7, slot = orig >> 3;
    int wid = (xcd < 4 ? xcd * 124 : 496 + (xcd - 4) * 123) + slot;
    int rt = wid & 3;           // row tile (256 rows)
    int cs = wid >> 2;          // 0..246 column chunk
    int cls = cs / NSUB;
    int sub = cs - cls * NSUB;
    int t0 = (NTILE * sub) / NSUB, t1 = (NTILE * (sub + 1)) / NSUB;

    int tid = threadIdx.x;
    int wave = tid >> 6, lane = tid & 63;
    int lg = lane >> 4, lm = lane & 15;
    int wrb = rt * 256 + wave * 64;   // this wave owns rows [wrb, wrb+64)

    // stage-thread mapping (R10): col c = tid>>4, 64B f32 segment seg = tid&15
    int c   = tid >> 4;
    int seg = tid & 15;
    int skk = seg >> 1;
    int sidx0 = skk * 64 + ((seg & 1) * 2) * 16 + c;
    unsigned sb0 = (unsigned)(sidx0 * 16) ^ (unsigned)(skk << 4);
    unsigned sb1 = (unsigned)((sidx0 + 16) * 16) ^ (unsigned)(skk << 4);
    const float* qbase = Qf + (size_t)cls * CACHE * DDIM + seg * 16;

    // A fragments (log2-scaled)
    bf16x8 afrag[4][8];
    #pragma unroll
    for (int f = 0; f < 4; ++f)
        #pragma unroll
        for (int kk = 0; kk < 8; ++kk)
            afrag[f][kk] = *reinterpret_cast<const bf16x8*>(
                Abf + (size_t)(wrb + f * 16 + lm) * DDIM + kk * 32 + lg * 8);

    float tacc[4][4] = {}, sacc[4][4] = {};

    // two named staging reg sets
    f32x4 sA0, sA1, sA2, sA3, sB0, sB1, sB2, sB3;
    bool okA, okB;

#define SLOAD1(R0, R1, R2, R3, OK, t) do {                                    \
        int _col = (t) * 16 + c;                                              \
        OK = _col < CACHE;                                                    \
        const f32x4* _src = reinterpret_cast<const f32x4*>(                   \
            qbase + (size_t)(OK ? _col : CACHE - 1) * DDIM);                  \
        R0 = _src[0]; R1 = _src[1]; R2 = _src[2]; R3 = _src[3];               \
    } while (0)

#define CVTW1(R0, R1, R2, R3, OK, buf) do {                                   \
        bf16x8 _p0, _p1;                                                      \
        _Pragma("unroll")                                                     \
        for (int j = 0; j < 4; ++j) {                                         \
            _p0[j]     = (__bf16)R0[j];                                       \
            _p0[j + 4] = (__bf16)R1[j];                                       \
            _p1[j]     = (__bf16)R2[j];                                       \
            _p1[j + 4] = (__bf16)R3[j];                                       \
        }                                                                     \
        bf16x8 _z = {};                                                       \
        if (!OK) { _p0 = _z; _p1 = _z; }                                      \
        *reinterpret_cast<bf16x8*>(&lds[buf][sb0]) = _p0;                     \
        *reinterpret_cast<bf16x8*>(&lds[buf][sb1]) = _p1;                     \
    } while (0)

#define COMPUTE(buf) do {                                                     \
        bf16x8 bfrag[8];                                                      \
        _Pragma("unroll")                                                     \
        for (int kk = 0; kk < 8; ++kk)                                        \
            bfrag[kk] = *reinterpret_cast<const bf16x8*>(                     \
                &lds[buf][(unsigned)((kk * 64 + lane) * 16) ^ (unsigned)(kk << 4)]); \
        f32x4 acc[4];                                                         \
        _Pragma("unroll")                                                     \
        for (int f = 0; f < 4; ++f) acc[f] = (f32x4){0.f, 0.f, 0.f, 0.f};     \
        _Pragma("unroll")                                                     \
        for (int kk = 0; kk < 8; ++kk)                                        \
            _Pragma("unroll")                                                 \
            for (int f = 0; f < 4; ++f)                                       \
                acc[f] = __builtin_amdgcn_mfma_f32_16x16x32_bf16(             \
                    afrag[f][kk], bfrag[kk], acc[f], 0, 0, 0);                \
        _Pragma("unroll")                                                     \
        for (int f = 0; f < 4; ++f)                                           \
            _Pragma("unroll")                                                 \
            for (int r = 0; r < 4; ++r) {                                     \
                float v = acc[f][r];            /* s * log2(e) */             \
                tacc[f][r] += EXP2(v);          /* pad cols: v=0 -> e=1 */    \
                sacc[f][r] += v;                                              \
            }                                                                 \
    } while (0)

#define SLOADA(t) SLOAD1(sA0, sA1, sA2, sA3, okA, t)
#define SLOADB(t) SLOAD1(sB0, sB1, sB2, sB3, okB, t)
#define CVTWRITEA(buf) CVTW1(sA0, sA1, sA2, sA3, okA, buf)
#define CVTWRITEB(buf) CVTW1(sB0, sB1, sB2, sB3, okB, buf)

    int nt = t1 - t0;

    // prologue: window 0 staged via A; window 1 preloaded into B
    SLOADA(t0);
    CVTWRITEA(0);
    if (nt > 1) SLOADB(t0 + 1);
    BARRIER_NODRAIN();

    int cur = 0, it = 0;
    for (;;) {
        // even-position window: prefetch t+2 into A (freed 2 windows ago),
        // compute current, publish B (loaded last window) into next buffer.
        if (it + 2 < nt) SLOADA(t0 + it + 2);
        COMPUTE(cur);
        if (it + 1 < nt) CVTWRITEB(cur ^ 1);
        BARRIER_NODRAIN();
        cur ^= 1; ++it;
        if (it >= nt) break;

        if (it + 2 < nt) SLOADB(t0 + it + 2);
        COMPUTE(cur);
        if (it + 1 < nt) CVTWRITEA(cur ^ 1);
        BARRIER_NODRAIN();
        cur ^= 1; ++it;
        if (it >= nt) break;
    }
#undef SLOAD1
#undef CVTW1
#undef COMPUTE
#undef SLOADA
#undef SLOADB
#undef CVTWRITEA
#undef CVTWRITEB

    // reduce across the 16 column-lanes (lm) and store per-chunk partials
    #pragma unroll
    for (int f = 0; f < 4; ++f)
        #pragma unroll
        for (int r = 0; r < 4; ++r) {
            float t = tacc[f][r], s = sacc[f][r];
            #pragma unroll
            for (int m = 1; m < 16; m <<= 1) {
                t += __shfl_xor(t, m);
                s += __shfl_xor(s, m);
            }
            if (lm == 0) {
                int row = wrb + f * 16 + lg * 4 + r;
                float mp = (row < NROWS && y[row % NANCH] == cls) ? 1.0f : 0.0f;
                size_t idx = (size_t)cs * 1024 + row;
                Pt[idx] = t; Pe[idx] = mp * t; Ps[idx] = mp * s;
            }
        }
}

// ---- per-row finalization: 16 blocks x 256 thr, 4 threads per row ----
__global__ __launch_bounds__(256) void reduce_rows(const float* __restrict__ Pt,
                                                   const float* __restrict__ Pe,
                                                   const float* __restrict__ Ps,
                                                   float* __restrict__ rowloss) {
    int tid = threadIdx.x;
    int row = blockIdx.x * 64 + (tid >> 2);   // 0..1023
    int part = tid & 3;
    float tot = 0.f, pe = 0.f, ps = 0.f;
    for (int c = part; c < NCHUNK; c += 4) {
        size_t idx = (size_t)c * 1024 + row;
        tot += Pt[idx]; pe += Pe[idx]; ps += Ps[idx];
    }
    tot += __shfl_xor(tot, 1); pe += __shfl_xor(pe, 1); ps += __shfl_xor(ps, 1);
    tot += __shfl_xor(tot, 2); pe += __shfl_xor(pe, 2); ps += __shfl_xor(ps, 2);
    if (part == 0) {
        float r = 0.f;
        if (row < NROWS) {
            // tot includes all 19*8=152 pad cols (e=1 each); pe the 8 pads of pos class
            float ns    = tot - pe - 144.0f;        // sum exp over true negatives
            float pos_e = pe - 8.0f;                // sum exp over true positives
            float pos_s = ps * LN2;                 // sum of s over positives (ln domain)
            // sum_pos log(e^s + ns) ~= 5000*log(ns) + pos_e/ns   (first-order log1p)
            float sum_logprob = pos_s - (5000.0f * logf(ns) + pos_e / ns);
            r = -sum_logprob / (5000.0f + 1e-4f);
        }
        rowloss[row] = r;
    }
}

// ---- final mean over 1020 rows ----
__global__ __launch_bounds__(256) void pass3_kernel(const float* __restrict__ rowloss,
                                                    float* __restrict__ out) {
    float local = 0.f;
    for (int n = threadIdx.x; n < 1024; n += 256) local += rowloss[n];
    #pragma unroll
    for (int m = 1; m < 64; m <<= 1) local += __shfl_xor(local, m);
    __shared__ float sb[4];
    if ((threadIdx.x & 63) == 0) sb[threadIdx.x >> 6] = local;
    __syncthreads();
    if (threadIdx.x == 0)
        out[0] = (sb[0] + sb[1] + sb[2] + sb[3]) * (1.0f / (float)NROWS);
}

extern "C" void kernel_launch(void* const* d_in, const int* in_sizes, int n_in,
                              void* d_out, int out_size, void* d_ws, size_t ws_size,
                              hipStream_t stream) {
    const float* X  = (const float*)d_in[0];   // [102][10][256]
    const int*   y  = (const int*)d_in[1];     // [102]
    const float* Qf = (const float*)d_in[2];   // [19][5000][256]
    float* out = (float*)d_out;

    char* ws = (char*)d_ws;
    // ws layout (bytes):
    //   Abf [1024][256] bf16           :    524,288
    //   Pt  [247][1024] f32            :  1,011,712
    //   Pe  [247][1024] f32            :  1,011,712
    //   Ps  [247][1024] f32            :  1,011,712
    //   rowloss [1024] f32             :      4,096
    unsigned short* Abf = (unsigned short*)(ws);
    float* Pt      = (float*)(ws + 524288);
    float* Pe      = (float*)(ws + 1536000);
    float* Ps      = (float*)(ws + 2547712);
    float* rowloss = (float*)(ws + 3559424);

    conv_anchor2<<<1024, 256, 0, stream>>>(X, Abf);
    pass1_kernel<<<NWG, 256, 0, stream>>>(Abf, Qf, y, Pt, Pe, Ps);  // 988 blocks
    reduce_rows<<<16, 256, 0, stream>>>(Pt, Pe, Ps, rowloss);
    pass3_kernel<<<1, 256, 0, stream>>>(rowloss, out);
}

// Round 18
// 112.375 us; speedup vs baseline: 3.4576x; 3.4576x over previous
//
#include <hip/hip_runtime.h>
#include <hip/hip_bf16.h>
#include <stdint.h>

// ---- problem constants ----
#define NCLS   19
#define CACHE  5000
#define NTILE  313            // 16-col tiles per class (313*16 = 5008, 8 pad cols)
#define DDIM   256
#define NANCH  102
#define NVIEW  10
#define NROWS  1020
#define NSUB   13             // column sub-chunks per class
#define NCHUNK (NCLS*NSUB)    // 247
#define NWG    (4*NCHUNK)     // 988 pass1 blocks
#define SCALE_A 20.6099319733f   // (1/0.07) * log2(e): MFMA acc = s * log2(e)
#define LN2     0.69314718056f

using bf16x8 = __attribute__((ext_vector_type(8))) __bf16;
using f32x4  = __attribute__((ext_vector_type(4))) float;

#if __has_builtin(__builtin_amdgcn_exp2f)
#define EXP2(x) __builtin_amdgcn_exp2f(x)
#else
#define EXP2(x) __expf((x) * LN2)
#endif

// Raw barrier WITHOUT the vmcnt(0) drain __syncthreads emits (m97/m233).
#define BARRIER_NODRAIN() do {                                   \
        asm volatile("s_waitcnt lgkmcnt(0)" ::: "memory");       \
        __builtin_amdgcn_sched_barrier(0);                       \
        __builtin_amdgcn_s_barrier();                            \
        __builtin_amdgcn_sched_barrier(0);                       \
    } while (0)

// ---- fused pass: A-conversion + staging + GEMM + exp2 accumulation ----
// R16 structure (best measured) with conv_anchor2 fused into the prologue:
// each block loads its 256 A-rows directly from X (f32, L3-resident), scales
// by (1/T)*log2(e) and converts to bf16 fragments in-register. No Abf buffer.
__global__ __launch_bounds__(256, 2) void pass1_kernel(
    const float* __restrict__ X, const float* __restrict__ Qf,
    const int* __restrict__ y,
    float* __restrict__ Pt, float* __restrict__ Pe, float* __restrict__ Ps)
{
    __shared__ unsigned char lds[2][8192];   // 2 x 8KB bf16 fragment tiles

    // bijective XCD swizzle (m204): nwg=988, 8 XCDs, q=123, r=4.
    int orig = blockIdx.x;
    int xcd = orig & 7, slot = orig >> 3;
    int wid = (xcd < 4 ? xcd * 124 : 496 + (xcd - 4) * 123) + slot;
    int rt = wid & 3;           // row tile (256 rows)
    int cs = wid >> 2;          // 0..246 column chunk
    int cls = cs / NSUB;
    int sub = cs - cls * NSUB;
    int t0 = (NTILE * sub) / NSUB, t1 = (NTILE * (sub + 1)) / NSUB;

    int tid = threadIdx.x;
    int wave = tid >> 6, lane = tid & 63;
    int lg = lane >> 4, lm = lane & 15;
    int wrb = rt * 256 + wave * 64;   // this wave owns rows [wrb, wrb+64)

    // stage-thread mapping (R10): col c = tid>>4, 64B f32 segment seg = tid&15
    int c   = tid >> 4;
    int seg = tid & 15;
    int skk = seg >> 1;
    int sidx0 = skk * 64 + ((seg & 1) * 2) * 16 + c;
    unsigned sb0 = (unsigned)(sidx0 * 16) ^ (unsigned)(skk << 4);
    unsigned sb1 = (unsigned)((sidx0 + 16) * 16) ^ (unsigned)(skk << 4);
    const float* qbase = Qf + (size_t)cls * CACHE * DDIM + seg * 16;

    // A fragments: loaded straight from X (view-major row n -> X[n%102][n/102]),
    // scaled by SCALE_A, converted to bf16 in-register. frag f covers rows
    // wrb+f*16, row-in-frag = lane&15; k = kk*32 + lg*8 .. +8.
    bf16x8 afrag[4][8];
    #pragma unroll
    for (int f = 0; f < 4; ++f) {
        int row = wrb + f * 16 + lm;
        bool rok = row < NROWS;
        int a = row % NANCH, vv = row / NANCH;
        const float* xsrc = X + ((size_t)(rok ? a * NVIEW + vv : 0)) * DDIM + lg * 8;
        #pragma unroll
        for (int kk = 0; kk < 8; ++kk) {
            bf16x8 v = {};
            if (rok) {
                const f32x4* p = reinterpret_cast<const f32x4*>(xsrc + kk * 32);
                f32x4 u0 = p[0], u1 = p[1];
                #pragma unroll
                for (int j = 0; j < 4; ++j) {
                    v[j]     = (__bf16)(u0[j] * SCALE_A);
                    v[j + 4] = (__bf16)(u1[j] * SCALE_A);
                }
            }
            afrag[f][kk] = v;
        }
    }

    float tacc[4][4] = {}, sacc[4][4] = {};

    // two named staging reg sets
    f32x4 sA0, sA1, sA2, sA3, sB0, sB1, sB2, sB3;
    bool okA, okB;

#define SLOAD1(R0, R1, R2, R3, OK, t) do {                                    \
        int _col = (t) * 16 + c;                                              \
        OK = _col < CACHE;                                                    \
        const f32x4* _src = reinterpret_cast<const f32x4*>(                   \
            qbase + (size_t)(OK ? _col : CACHE - 1) * DDIM);                  \
        R0 = _src[0]; R1 = _src[1]; R2 = _src[2]; R3 = _src[3];               \
    } while (0)

#define CVTW1(R0, R1, R2, R3, OK, buf) do {                                   \
        bf16x8 _p0, _p1;                                                      \
        _Pragma("unroll")                                                     \
        for (int j = 0; j < 4; ++j) {                                         \
            _p0[j]     = (__bf16)R0[j];                                       \
            _p0[j + 4] = (__bf16)R1[j];                                       \
            _p1[j]     = (__bf16)R2[j];                                       \
            _p1[j + 4] = (__bf16)R3[j];                                       \
        }                                                                     \
        bf16x8 _z = {};                                                       \
        if (!OK) { _p0 = _z; _p1 = _z; }                                      \
        *reinterpret_cast<bf16x8*>(&lds[buf][sb0]) = _p0;                     \
        *reinterpret_cast<bf16x8*>(&lds[buf][sb1]) = _p1;                     \
    } while (0)

#define COMPUTE(buf) do {                                                     \
        bf16x8 bfrag[8];                                                      \
        _Pragma("unroll")                                                     \
        for (int kk = 0; kk < 8; ++kk)                                        \
            bfrag[kk] = *reinterpret_cast<const bf16x8*>(                     \
                &lds[buf][(unsigned)((kk * 64 + lane) * 16) ^ (unsigned)(kk << 4)]); \
        f32x4 acc[4];                                                         \
        _Pragma("unroll")                                                     \
        for (int f = 0; f < 4; ++f) acc[f] = (f32x4){0.f, 0.f, 0.f, 0.f};     \
        _Pragma("unroll")                                                     \
        for (int kk = 0; kk < 8; ++kk)                                        \
            _Pragma("unroll")                                                 \
            for (int f = 0; f < 4; ++f)                                       \
                acc[f] = __builtin_amdgcn_mfma_f32_16x16x32_bf16(             \
                    afrag[f][kk], bfrag[kk], acc[f], 0, 0, 0);                \
        _Pragma("unroll")                                                     \
        for (int f = 0; f < 4; ++f)                                           \
            _Pragma("unroll")                                                 \
            for (int r = 0; r < 4; ++r) {                                     \
                float v = acc[f][r];            /* s * log2(e) */             \
                tacc[f][r] += EXP2(v);          /* pad cols: v=0 -> e=1 */    \
                sacc[f][r] += v;                                              \
            }                                                                 \
    } while (0)

#define SLOADA(t) SLOAD1(sA0, sA1, sA2, sA3, okA, t)
#define SLOADB(t) SLOAD1(sB0, sB1, sB2, sB3, okB, t)
#define CVTWRITEA(buf) CVTW1(sA0, sA1, sA2, sA3, okA, buf)
#define CVTWRITEB(buf) CVTW1(sB0, sB1, sB2, sB3, okB, buf)

    int nt = t1 - t0;

    // prologue: window 0 staged via A; window 1 preloaded into B
    SLOADA(t0);
    CVTWRITEA(0);
    if (nt > 1) SLOADB(t0 + 1);
    BARRIER_NODRAIN();

    int cur = 0, it = 0;
    for (;;) {
        // even-position window: prefetch t+2 into A (freed 2 windows ago),
        // compute current, publish B (loaded last window) into next buffer.
        if (it + 2 < nt) SLOADA(t0 + it + 2);
        COMPUTE(cur);
        if (it + 1 < nt) CVTWRITEB(cur ^ 1);
        BARRIER_NODRAIN();
        cur ^= 1; ++it;
        if (it >= nt) break;

        if (it + 2 < nt) SLOADB(t0 + it + 2);
        COMPUTE(cur);
        if (it + 1 < nt) CVTWRITEA(cur ^ 1);
        BARRIER_NODRAIN();
        cur ^= 1; ++it;
        if (it >= nt) break;
    }
#undef SLOAD1
#undef CVTW1
#undef COMPUTE
#undef SLOADA
#undef SLOADB
#undef CVTWRITEA
#undef CVTWRITEB

    // reduce across the 16 column-lanes (lm) and store per-chunk partials
    #pragma unroll
    for (int f = 0; f < 4; ++f)
        #pragma unroll
        for (int r = 0; r < 4; ++r) {
            float t = tacc[f][r], s = sacc[f][r];
            #pragma unroll
            for (int m = 1; m < 16; m <<= 1) {
                t += __shfl_xor(t, m);
                s += __shfl_xor(s, m);
            }
            if (lm == 0) {
                int row = wrb + f * 16 + lg * 4 + r;
                float mp = (row < NROWS && y[row % NANCH] == cls) ? 1.0f : 0.0f;
                size_t idx = (size_t)cs * 1024 + row;
                Pt[idx] = t; Pe[idx] = mp * t; Ps[idx] = mp * s;
            }
        }
}

// ---- per-row finalization: 16 blocks x 256 thr, 4 threads per row ----
__global__ __launch_bounds__(256) void reduce_rows(const float* __restrict__ Pt,
                                                   const float* __restrict__ Pe,
                                                   const float* __restrict__ Ps,
                                                   float* __restrict__ rowloss) {
    int tid = threadIdx.x;
    int row = blockIdx.x * 64 + (tid >> 2);   // 0..1023
    int part = tid & 3;
    float tot = 0.f, pe = 0.f, ps = 0.f;
    for (int c = part; c < NCHUNK; c += 4) {
        size_t idx = (size_t)c * 1024 + row;
        tot += Pt[idx]; pe += Pe[idx]; ps += Ps[idx];
    }
    tot += __shfl_xor(tot, 1); pe += __shfl_xor(pe, 1); ps += __shfl_xor(ps, 1);
    tot += __shfl_xor(tot, 2); pe += __shfl_xor(pe, 2); ps += __shfl_xor(ps, 2);
    if (part == 0) {
        float r = 0.f;
        if (row < NROWS) {
            // tot includes all 19*8=152 pad cols (e=1 each); pe the 8 pads of pos class
            float ns    = tot - pe - 144.0f;        // sum exp over true negatives
            float pos_e = pe - 8.0f;                // sum exp over true positives
            float pos_s = ps * LN2;                 // sum of s over positives (ln domain)
            // sum_pos log(e^s + ns) ~= 5000*log(ns) + pos_e/ns   (first-order log1p)
            float sum_logprob = pos_s - (5000.0f * logf(ns) + pos_e / ns);
            r = -sum_logprob / (5000.0f + 1e-4f);
        }
        rowloss[row] = r;
    }
}

// ---- final mean over 1020 rows ----
__global__ __launch_bounds__(256) void pass3_kernel(const float* __restrict__ rowloss,
                                                    float* __restrict__ out) {
    float local = 0.f;
    for (int n = threadIdx.x; n < 1024; n += 256) local += rowloss[n];
    #pragma unroll
    for (int m = 1; m < 64; m <<= 1) local += __shfl_xor(local, m);
    __shared__ float sb[4];
    if ((threadIdx.x & 63) == 0) sb[threadIdx.x >> 6] = local;
    __syncthreads();
    if (threadIdx.x == 0)
        out[0] = (sb[0] + sb[1] + sb[2] + sb[3]) * (1.0f / (float)NROWS);
}

extern "C" void kernel_launch(void* const* d_in, const int* in_sizes, int n_in,
                              void* d_out, int out_size, void* d_ws, size_t ws_size,
                              hipStream_t stream) {
    const float* X  = (const float*)d_in[0];   // [102][10][256]
    const int*   y  = (const int*)d_in[1];     // [102]
    const float* Qf = (const float*)d_in[2];   // [19][5000][256]
    float* out = (float*)d_out;

    char* ws = (char*)d_ws;
    // ws layout (bytes):
    //   Pt  [247][1024] f32            :  1,011,712
    //   Pe  [247][1024] f32            :  1,011,712
    //   Ps  [247][1024] f32            :  1,011,712
    //   rowloss [1024] f32             :      4,096
    float* Pt      = (float*)(ws);
    float* Pe      = (float*)(ws + 1011712);
    float* Ps      = (float*)(ws + 2023424);
    float* rowloss = (float*)(ws + 3035136);

    pass1_kernel<<<NWG, 256, 0, stream>>>(X, Qf, y, Pt, Pe, Ps);  // 988 blocks
    reduce_rows<<<16, 256, 0, stream>>>(Pt, Pe, Ps, rowloss);
    pass3_kernel<<<1, 256, 0, stream>>>(rowloss, out);
}

// Round 19
// 101.764 us; speedup vs baseline: 3.8181x; 1.1043x over previous
//
#include <hip/hip_runtime.h>
#include <hip/hip_bf16.h>
#include <stdint.h>

// ---- problem constants ----
#define NCLS   19
#define CACHE  5000
#define NTILE  313            // 16-col tiles per class (313*16 = 5008, 8 pad cols)
#define DDIM   256
#define NANCH  102
#define NVIEW  10
#define NROWS  1020
#define NSUB   13             // column sub-chunks per class
#define NCHUNK (NCLS*NSUB)    // 247
#define NWG    (4*NCHUNK)     // 988 pass1 blocks
#define SCALE_A 20.6099319733f   // (1/0.07) * log2(e): MFMA acc = s * log2(e)
#define LN2     0.69314718056f

using bf16x8 = __attribute__((ext_vector_type(8))) __bf16;
using f32x4  = __attribute__((ext_vector_type(4))) float;

#if __has_builtin(__builtin_amdgcn_exp2f)
#define EXP2(x) __builtin_amdgcn_exp2f(x)
#else
#define EXP2(x) __expf((x) * LN2)
#endif

static __device__ __forceinline__ unsigned short f2bf(float x) {
    unsigned int u = __float_as_uint(x);
    unsigned int r = (u + 0x7FFFu + ((u >> 16) & 1u)) >> 16;
    return (unsigned short)r;
}

// Raw barrier WITHOUT the vmcnt(0) drain __syncthreads emits (m97/m233).
#define BARRIER_NODRAIN() do {                                   \
        asm volatile("s_waitcnt lgkmcnt(0)" ::: "memory");       \
        __builtin_amdgcn_sched_barrier(0);                       \
        __builtin_amdgcn_s_barrier();                            \
        __builtin_amdgcn_sched_barrier(0);                       \
    } while (0)

// ---- anchors: view-major [1024][256] bf16, pre-scaled by (1/T)*log2(e) ----
// One-shot coalesced pass (1 MB). R18 proved fusing this into pass1 costs 7x
// its own runtime in replicated per-block gather overhead.
__global__ __launch_bounds__(256) void conv_anchor2(const float* __restrict__ X,
                                                    unsigned short* __restrict__ Abf) {
    int n = blockIdx.x;     // 0..1023
    int k = threadIdx.x;    // 0..255
    float v = 0.f;
    if (n < NROWS) {
        int vv = n / NANCH, a = n - vv * NANCH;
        v = X[((size_t)a * NVIEW + vv) * DDIM + k] * SCALE_A;
    }
    Abf[(size_t)n * DDIM + k] = f2bf(v);
}

// ---- fused pass: R16 structure (session optimum) ----
// 988 blocks x 256 thr, 64 rows/wave A-resident, fused f32->bf16 staging with
// distance-2 register prefetch, XOR fragment map, non-draining barriers.
// Register ceiling (VGPR+AGPR ~250, R6/R17) pins this at 2 waves/SIMD.
__global__ __launch_bounds__(256, 2) void pass1_kernel(
    const unsigned short* __restrict__ Abf, const float* __restrict__ Qf,
    const int* __restrict__ y,
    float* __restrict__ Pt, float* __restrict__ Pe, float* __restrict__ Ps)
{
    __shared__ unsigned char lds[2][8192];   // 2 x 8KB bf16 fragment tiles

    // bijective XCD swizzle (m204): nwg=988, 8 XCDs, q=123, r=4.
    int orig = blockIdx.x;
    int xcd = orig & 7, slot = orig >> 3;
    int wid = (xcd < 4 ? xcd * 124 : 496 + (xcd - 4) * 123) + slot;
    int rt = wid & 3;           // row tile (256 rows)
    int cs = wid >> 2;          // 0..246 column chunk
    int cls = cs / NSUB;
    int sub = cs - cls * NSUB;
    int t0 = (NTILE * sub) / NSUB, t1 = (NTILE * (sub + 1)) / NSUB;

    int tid = threadIdx.x;
    int wave = tid >> 6, lane = tid & 63;
    int lg = lane >> 4, lm = lane & 15;
    int wrb = rt * 256 + wave * 64;   // this wave owns rows [wrb, wrb+64)

    // stage-thread mapping (R10): col c = tid>>4, 64B f32 segment seg = tid&15
    int c   = tid >> 4;
    int seg = tid & 15;
    int skk = seg >> 1;
    int sidx0 = skk * 64 + ((seg & 1) * 2) * 16 + c;
    unsigned sb0 = (unsigned)(sidx0 * 16) ^ (unsigned)(skk << 4);
    unsigned sb1 = (unsigned)((sidx0 + 16) * 16) ^ (unsigned)(skk << 4);
    const float* qbase = Qf + (size_t)cls * CACHE * DDIM + seg * 16;

    // A fragments (log2-scaled)
    bf16x8 afrag[4][8];
    #pragma unroll
    for (int f = 0; f < 4; ++f)
        #pragma unroll
        for (int kk = 0; kk < 8; ++kk)
            afrag[f][kk] = *reinterpret_cast<const bf16x8*>(
                Abf + (size_t)(wrb + f * 16 + lm) * DDIM + kk * 32 + lg * 8);

    float tacc[4][4] = {}, sacc[4][4] = {};

    // two named staging reg sets
    f32x4 sA0, sA1, sA2, sA3, sB0, sB1, sB2, sB3;
    bool okA, okB;

#define SLOAD1(R0, R1, R2, R3, OK, t) do {                                    \
        int _col = (t) * 16 + c;                                              \
        OK = _col < CACHE;                                                    \
        const f32x4* _src = reinterpret_cast<const f32x4*>(                   \
            qbase + (size_t)(OK ? _col : CACHE - 1) * DDIM);                  \
        R0 = _src[0]; R1 = _src[1]; R2 = _src[2]; R3 = _src[3];               \
    } while (0)

#define CVTW1(R0, R1, R2, R3, OK, buf) do {                                   \
        bf16x8 _p0, _p1;                                                      \
        _Pragma("unroll")                                                     \
        for (int j = 0; j < 4; ++j) {                                         \
            _p0[j]     = (__bf16)R0[j];                                       \
            _p0[j + 4] = (__bf16)R1[j];                                       \
            _p1[j]     = (__bf16)R2[j];                                       \
            _p1[j + 4] = (__bf16)R3[j];                                       \
        }                                                                     \
        bf16x8 _z = {};                                                       \
        if (!OK) { _p0 = _z; _p1 = _z; }                                      \
        *reinterpret_cast<bf16x8*>(&lds[buf][sb0]) = _p0;                     \
        *reinterpret_cast<bf16x8*>(&lds[buf][sb1]) = _p1;                     \
    } while (0)

#define COMPUTE(buf) do {                                                     \
        bf16x8 bfrag[8];                                                      \
        _Pragma("unroll")                                                     \
        for (int kk = 0; kk < 8; ++kk)                                        \
            bfrag[kk] = *reinterpret_cast<const bf16x8*>(                     \
                &lds[buf][(unsigned)((kk * 64 + lane) * 16) ^ (unsigned)(kk << 4)]); \
        f32x4 acc[4];                                                         \
        _Pragma("unroll")                                                     \
        for (int f = 0; f < 4; ++f) acc[f] = (f32x4){0.f, 0.f, 0.f, 0.f};     \
        _Pragma("unroll")                                                     \
        for (int kk = 0; kk < 8; ++kk)                                        \
            _Pragma("unroll")                                                 \
            for (int f = 0; f < 4; ++f)                                       \
                acc[f] = __builtin_amdgcn_mfma_f32_16x16x32_bf16(             \
                    afrag[f][kk], bfrag[kk], acc[f], 0, 0, 0);                \
        _Pragma("unroll")                                                     \
        for (int f = 0; f < 4; ++f)                                           \
            _Pragma("unroll")                                                 \
            for (int r = 0; r < 4; ++r) {                                     \
                float v = acc[f][r];            /* s * log2(e) */             \
                tacc[f][r] += EXP2(v);          /* pad cols: v=0 -> e=1 */    \
                sacc[f][r] += v;                                              \
            }                                                                 \
    } while (0)

#define SLOADA(t) SLOAD1(sA0, sA1, sA2, sA3, okA, t)
#define SLOADB(t) SLOAD1(sB0, sB1, sB2, sB3, okB, t)
#define CVTWRITEA(buf) CVTW1(sA0, sA1, sA2, sA3, okA, buf)
#define CVTWRITEB(buf) CVTW1(sB0, sB1, sB2, sB3, okB, buf)

    int nt = t1 - t0;

    // prologue: window 0 staged via A; window 1 preloaded into B
    SLOADA(t0);
    CVTWRITEA(0);
    if (nt > 1) SLOADB(t0 + 1);
    BARRIER_NODRAIN();

    int cur = 0, it = 0;
    for (;;) {
        // even-position window: prefetch t+2 into A (freed 2 windows ago),
        // compute current, publish B (loaded last window) into next buffer.
        if (it + 2 < nt) SLOADA(t0 + it + 2);
        COMPUTE(cur);
        if (it + 1 < nt) CVTWRITEB(cur ^ 1);
        BARRIER_NODRAIN();
        cur ^= 1; ++it;
        if (it >= nt) break;

        if (it + 2 < nt) SLOADB(t0 + it + 2);
        COMPUTE(cur);
        if (it + 1 < nt) CVTWRITEA(cur ^ 1);
        BARRIER_NODRAIN();
        cur ^= 1; ++it;
        if (it >= nt) break;
    }
#undef SLOAD1
#undef CVTW1
#undef COMPUTE
#undef SLOADA
#undef SLOADB
#undef CVTWRITEA
#undef CVTWRITEB

    // reduce across the 16 column-lanes (lm) and store per-chunk partials
    #pragma unroll
    for (int f = 0; f < 4; ++f)
        #pragma unroll
        for (int r = 0; r < 4; ++r) {
            float t = tacc[f][r], s = sacc[f][r];
            #pragma unroll
            for (int m = 1; m < 16; m <<= 1) {
                t += __shfl_xor(t, m);
                s += __shfl_xor(s, m);
            }
            if (lm == 0) {
                int row = wrb + f * 16 + lg * 4 + r;
                float mp = (row < NROWS && y[row % NANCH] == cls) ? 1.0f : 0.0f;
                size_t idx = (size_t)cs * 1024 + row;
                Pt[idx] = t; Pe[idx] = mp * t; Ps[idx] = mp * s;
            }
        }
}

// ---- per-row finalization: 16 blocks x 256 thr, 4 threads per row ----
__global__ __launch_bounds__(256) void reduce_rows(const float* __restrict__ Pt,
                                                   const float* __restrict__ Pe,
                                                   const float* __restrict__ Ps,
                                                   float* __restrict__ rowloss) {
    int tid = threadIdx.x;
    int row = blockIdx.x * 64 + (tid >> 2);   // 0..1023
    int part = tid & 3;
    float tot = 0.f, pe = 0.f, ps = 0.f;
    for (int c = part; c < NCHUNK; c += 4) {
        size_t idx = (size_t)c * 1024 + row;
        tot += Pt[idx]; pe += Pe[idx]; ps += Ps[idx];
    }
    tot += __shfl_xor(tot, 1); pe += __shfl_xor(pe, 1); ps += __shfl_xor(ps, 1);
    tot += __shfl_xor(tot, 2); pe += __shfl_xor(pe, 2); ps += __shfl_xor(ps, 2);
    if (part == 0) {
        float r = 0.f;
        if (row < NROWS) {
            // tot includes all 19*8=152 pad cols (e=1 each); pe the 8 pads of pos class
            float ns    = tot - pe - 144.0f;        // sum exp over true negatives
            float pos_e = pe - 8.0f;                // sum exp over true positives
            float pos_s = ps * LN2;                 // sum of s over positives (ln domain)
            // sum_pos log(e^s + ns) ~= 5000*log(ns) + pos_e/ns   (first-order log1p)
            float sum_logprob = pos_s - (5000.0f * logf(ns) + pos_e / ns);
            r = -sum_logprob / (5000.0f + 1e-4f);
        }
        rowloss[row] = r;
    }
}

// ---- final mean over 1020 rows ----
__global__ __launch_bounds__(256) void pass3_kernel(const float* __restrict__ rowloss,
                                                    float* __restrict__ out) {
    float local = 0.f;
    for (int n = threadIdx.x; n < 1024; n += 256) local += rowloss[n];
    #pragma unroll
    for (int m = 1; m < 64; m <<= 1) local += __shfl_xor(local, m);
    __shared__ float sb[4];
    if ((threadIdx.x & 63) == 0) sb[threadIdx.x >> 6] = local;
    __syncthreads();
    if (threadIdx.x == 0)
        out[0] = (sb[0] + sb[1] + sb[2] + sb[3]) * (1.0f / (float)NROWS);
}

extern "C" void kernel_launch(void* const* d_in, const int* in_sizes, int n_in,
                              void* d_out, int out_size, void* d_ws, size_t ws_size,
                              hipStream_t stream) {
    const float* X  = (const float*)d_in[0];   // [102][10][256]
    const int*   y  = (const int*)d_in[1];     // [102]
    const float* Qf = (const float*)d_in[2];   // [19][5000][256]
    float* out = (float*)d_out;

    char* ws = (char*)d_ws;
    // ws layout (bytes):
    //   Abf [1024][256] bf16           :    524,288
    //   Pt  [247][1024] f32            :  1,011,712
    //   Pe  [247][1024] f32            :  1,011,712
    //   Ps  [247][1024] f32            :  1,011,712
    //   rowloss [1024] f32             :      4,096
    unsigned short* Abf = (unsigned short*)(ws);
    float* Pt      = (float*)(ws + 524288);
    float* Pe      = (float*)(ws + 1536000);
    float* Ps      = (float*)(ws + 2547712);
    float* rowloss = (float*)(ws + 3559424);

    conv_anchor2<<<1024, 256, 0, stream>>>(X, Abf);
    pass1_kernel<<<NWG, 256, 0, stream>>>(Abf, Qf, y, Pt, Pe, Ps);  // 988 blocks
    reduce_rows<<<16, 256, 0, stream>>>(Pt, Pe, Ps, rowloss);
    pass3_kernel<<<1, 256, 0, stream>>>(rowloss, out);
}